// Round 6
// baseline (178.034 us; speedup 1.0000x reference)
//
#include <hip/hip_runtime.h>
#include <hip/hip_fp16.h>
#include <math.h>

constexpr int D = 128;
constexpr int MAIN_BLOCKS = 1536;  // 6 blocks/CU
constexpr int BLOCK = 256;
constexpr int NROWS = 8192;

#define QSCALE 25.4f            // 127/5
#define TWO_S2 (2.0f * (5.0f / 127.0f) * (5.0f / 127.0f))

#if __has_builtin(__builtin_amdgcn_sdot4)
__device__ inline int dot4(unsigned a, unsigned b, int c) {
    return __builtin_amdgcn_sdot4(a, b, c, false);
}
#else
__device__ inline int dot4(unsigned a, unsigned b, int c) {
    c += (int)(char)(a) * (int)(char)(b);
    c += (int)(char)(a >> 8) * (int)(char)(b >> 8);
    c += (int)(char)(a >> 16) * (int)(char)(b >> 16);
    c += (int)(char)(a >> 24) * (int)(char)(b >> 24);
    return c;
}
#endif

__device__ inline int dot16B(uint4 a, uint4 b) {
    int d = 0;
    d = dot4(a.x, b.x, d); d = dot4(a.y, b.y, d);
    d = dot4(a.z, b.z, d); d = dot4(a.w, b.w, d);
    return d;
}

// prep: per row fp32 sq (exact) -> fp16 table, int8-quantized row.
// Extra last block: triplet dtype detection + zero out[0] for the atomic sum.
__global__ __launch_bounds__(256) void prep_kernel(const float* __restrict__ feat,
                                                   const unsigned long long* __restrict__ trip,
                                                   int n_slots,
                                                   __half* __restrict__ sqh,
                                                   unsigned* __restrict__ q8,
                                                   int* __restrict__ flag,
                                                   float* __restrict__ out, int N) {
    if (blockIdx.x == gridDim.x - 1) {
        if (threadIdx.x < 64) {
            int cnt = n_slots < 2048 ? n_slots : 2048;
            bool big = false;
            for (int idx = threadIdx.x; idx < cnt; idx += 64)
                big |= (trip[idx] >> 32) != 0ULL;
            unsigned long long b = __ballot(big);
            if (threadIdx.x == 0) {
                flag[0] = (b != 0ULL) ? 1 : 0; // 1 => int32
                out[0] = 0.0f;                 // d_out is poisoned each launch
            }
        }
        return;
    }
    int gidx = blockIdx.x * 256 + threadIdx.x;
    int row = gidx >> 5, lane = gidx & 31;
    if (row >= N) return;
    float4 v = ((const float4*)(feat + (size_t)row * D))[lane];
    float s = v.x * v.x + v.y * v.y + v.z * v.z + v.w * v.w;
#pragma unroll
    for (int m = 16; m >= 1; m >>= 1) s += __shfl_xor(s, m);
    if (lane == 0) sqh[row] = __float2half(s);
    int q0 = __float2int_rn(fminf(fmaxf(v.x * QSCALE, -127.f), 127.f));
    int q1 = __float2int_rn(fminf(fmaxf(v.y * QSCALE, -127.f), 127.f));
    int q2 = __float2int_rn(fminf(fmaxf(v.z * QSCALE, -127.f), 127.f));
    int q3 = __float2int_rn(fminf(fmaxf(v.w * QSCALE, -127.f), 127.f));
    unsigned p = (q0 & 255) | ((q1 & 255) << 8) | ((q2 & 255) << 16) | ((q3 & 255) << 24);
    q8[(size_t)row * 32 + lane] = p;
}

// 8 lanes/row: ONE dwordx4 per lane covers a full contiguous 128B row per
// instruction-group (tests 128B TA transaction granularity). 4x unroll ->
// 32 triplets/wave/iter, 12 independent row-load instructions in flight.
// z = (sq_j - sq_k) - 2*S^2*(dot(qi,qj) - dot(qi,qk)); sq_i cancels exactly.
// Every lane of an 8-group accumulates the loss -> divide by 8T at the end.
__global__ __launch_bounds__(256, 6) void triplet_kernel(const uint4* __restrict__ q8,
                                                         const void* __restrict__ trip_raw,
                                                         const __half* __restrict__ sqh,
                                                         const int* __restrict__ flag,
                                                         float* __restrict__ out,
                                                         int T, int N) {
    __shared__ uint4 sq_u4[NROWS * 2 / 16]; // 16 KB fp16 sq
    {
        const uint4* src = (const uint4*)sqh;
        int nvec = N * 2 / 16;
        for (int t = threadIdx.x; t < nvec; t += BLOCK) sq_u4[t] = src[t];
    }
    __syncthreads();
    const __half* sqs = (const __half*)sq_u4;

    const int lane = threadIdx.x & 63;
    const int sub = lane & 7;   // lane within 8-group
    const int g8 = lane >> 3;   // group 0..7
    const int wave = blockIdx.x * (BLOCK / 64) + (threadIdx.x >> 6);
    const int stride = gridDim.x * (BLOCK / 64) * 32;
    const bool m32 = (flag[0] != 0);
    const int* __restrict__ t32 = (const int*)trip_raw;
    const long long* __restrict__ t64 = (const long long*)trip_raw;

    int idx[4][3]; // [unit][i,j,k]
    {
        int t0 = wave * 32;
#pragma unroll
        for (int u = 0; u < 4; u++) {
            int t = t0 + u * 8 + g8;
            int tc = t < T ? t : T - 1;
            if (m32) {
                idx[u][0] = t32[3 * tc]; idx[u][1] = t32[3 * tc + 1]; idx[u][2] = t32[3 * tc + 2];
            } else {
                idx[u][0] = (int)t64[3 * tc]; idx[u][1] = (int)t64[3 * tc + 1]; idx[u][2] = (int)t64[3 * tc + 2];
            }
        }
    }

    double lsum = 0.0;
    for (int tb = wave * 32; tb < T; tb += stride) {
        uint4 A[4], B[4], C[4];
        float sqj[4], sqk[4];
#pragma unroll
        for (int u = 0; u < 4; u++) {
            A[u] = q8[(size_t)idx[u][0] * 8 + sub];
            B[u] = q8[(size_t)idx[u][1] * 8 + sub];
            C[u] = q8[(size_t)idx[u][2] * 8 + sub];
        }
#pragma unroll
        for (int u = 0; u < 4; u++) {
            sqj[u] = __half2float(sqs[idx[u][1]]);
            sqk[u] = __half2float(sqs[idx[u][2]]);
        }
        // prefetch next iteration's indices (independent of row loads)
        int tn = tb + stride;
#pragma unroll
        for (int u = 0; u < 4; u++) {
            int t = tn + u * 8 + g8;
            int tc = t < T ? t : T - 1;
            if (m32) {
                idx[u][0] = t32[3 * tc]; idx[u][1] = t32[3 * tc + 1]; idx[u][2] = t32[3 * tc + 2];
            } else {
                idx[u][0] = (int)t64[3 * tc]; idx[u][1] = (int)t64[3 * tc + 1]; idx[u][2] = (int)t64[3 * tc + 2];
            }
        }

        int dd[4];
#pragma unroll
        for (int u = 0; u < 4; u++) dd[u] = dot16B(A[u], B[u]) - dot16B(A[u], C[u]);
#pragma unroll
        for (int u = 0; u < 4; u++) {
            dd[u] += __shfl_xor(dd[u], 1);
            dd[u] += __shfl_xor(dd[u], 2);
            dd[u] += __shfl_xor(dd[u], 4);
        }
#pragma unroll
        for (int u = 0; u < 4; u++) {
            bool valid = (tb + u * 8 + g8) < T;
            float z = (sqj[u] - sqk[u]) - TWO_S2 * (float)dd[u];
            float loss = fmaxf(z, 0.0f) + __logf(1.0f + __expf(-fabsf(z)));
            lsum += valid ? (double)loss : 0.0;
        }
    }
#pragma unroll
    for (int m = 1; m < 64; m <<= 1) lsum += __shfl_xor(lsum, m);
    if (lane == 0)
        atomicAdd(out, (float)(lsum / (8.0 * (double)T)));
}

extern "C" void kernel_launch(void* const* d_in, const int* in_sizes, int n_in,
                              void* d_out, int out_size, void* d_ws, size_t ws_size,
                              hipStream_t stream) {
    const float* feat = (const float*)d_in[0];
    const void* trip = d_in[1];
    int N = in_sizes[0] / D;  // 8192
    int T = in_sizes[1] / 3;  // 1,000,000

    char* ws = (char*)d_ws;
    int* flag = (int*)ws;
    __half* sqh = (__half*)(ws + 256);
    size_t q8_off = (256 + 2 * (size_t)N + 255) & ~(size_t)255;
    unsigned* q8 = (unsigned*)(ws + q8_off);
    float* out = (float*)d_out;

    int prep_blocks = (N * 32) / 256 + 1; // last block: dtype detect + out zero
    prep_kernel<<<prep_blocks, 256, 0, stream>>>(feat, (const unsigned long long*)trip,
                                                 in_sizes[1], sqh, q8, flag, out, N);
    triplet_kernel<<<MAIN_BLOCKS, BLOCK, 0, stream>>>((const uint4*)q8, trip, sqh, flag,
                                                      out, T, N);
}

// Round 7
// 162.950 us; speedup vs baseline: 1.0926x; 1.0926x over previous
//
#include <hip/hip_runtime.h>
#include <hip/hip_fp16.h>
#include <math.h>

constexpr int D = 128;
constexpr int MAIN_BLOCKS = 1536;  // 6 blocks/CU
constexpr int BLOCK = 256;
constexpr int NROWS = 8192;

#define QSCALE 25.4f            // 127/5
#define TWO_S2 (2.0f * (5.0f / 127.0f) * (5.0f / 127.0f))

#if __has_builtin(__builtin_amdgcn_sdot4)
__device__ inline int dot4(unsigned a, unsigned b, int c) {
    return __builtin_amdgcn_sdot4(a, b, c, false);
}
#else
__device__ inline int dot4(unsigned a, unsigned b, int c) {
    c += (int)(char)(a) * (int)(char)(b);
    c += (int)(char)(a >> 8) * (int)(char)(b >> 8);
    c += (int)(char)(a >> 16) * (int)(char)(b >> 16);
    c += (int)(char)(a >> 24) * (int)(char)(b >> 24);
    return c;
}
#endif

__device__ inline int dot16B(uint4 a, uint4 b) {
    int d = 0;
    d = dot4(a.x, b.x, d); d = dot4(a.y, b.y, d);
    d = dot4(a.z, b.z, d); d = dot4(a.w, b.w, d);
    return d;
}

// prep: per row fp32 sq (exact) -> fp16 table, int8-quantized row.
// Extra last block: triplet dtype detection + zero out[0] for the atomic sum.
__global__ __launch_bounds__(256) void prep_kernel(const float* __restrict__ feat,
                                                   const unsigned long long* __restrict__ trip,
                                                   int n_slots,
                                                   __half* __restrict__ sqh,
                                                   unsigned* __restrict__ q8,
                                                   int* __restrict__ flag,
                                                   float* __restrict__ out, int N) {
    if (blockIdx.x == gridDim.x - 1) {
        if (threadIdx.x < 64) {
            int cnt = n_slots < 2048 ? n_slots : 2048;
            bool big = false;
            for (int idx = threadIdx.x; idx < cnt; idx += 64)
                big |= (trip[idx] >> 32) != 0ULL;
            unsigned long long b = __ballot(big);
            if (threadIdx.x == 0) {
                flag[0] = (b != 0ULL) ? 1 : 0; // 1 => int32
                out[0] = 0.0f;                 // d_out is poisoned each launch
            }
        }
        return;
    }
    int gidx = blockIdx.x * 256 + threadIdx.x;
    int row = gidx >> 5, lane = gidx & 31;
    if (row >= N) return;
    float4 v = ((const float4*)(feat + (size_t)row * D))[lane];
    float s = v.x * v.x + v.y * v.y + v.z * v.z + v.w * v.w;
#pragma unroll
    for (int m = 16; m >= 1; m >>= 1) s += __shfl_xor(s, m);
    if (lane == 0) sqh[row] = __float2half(s);
    int q0 = __float2int_rn(fminf(fmaxf(v.x * QSCALE, -127.f), 127.f));
    int q1 = __float2int_rn(fminf(fmaxf(v.y * QSCALE, -127.f), 127.f));
    int q2 = __float2int_rn(fminf(fmaxf(v.z * QSCALE, -127.f), 127.f));
    int q3 = __float2int_rn(fminf(fmaxf(v.w * QSCALE, -127.f), 127.f));
    unsigned p = (q0 & 255) | ((q1 & 255) << 8) | ((q2 & 255) << 16) | ((q3 & 255) << 24);
    q8[(size_t)row * 32 + lane] = p;
}

// 8 lanes/row, ONE dwordx4 per lane -> each 8-lane group covers one full
// contiguous 128B row per load instruction (128B transaction-granularity test).
// 2 units = 16 triplets/wave-iter, 6 independent row loads in flight.
// ALL state in named scalars (R6's idx[][] array spilled to scratch: 62MB
// WRITE_SIZE -- never again).
// z = (sq_j - sq_k) - 2*S^2*(dot(qi,qj) - dot(qi,qk)); sq_i cancels exactly.
// Every lane of an 8-group accumulates the loss -> divide by 8T at the end.
__global__ __launch_bounds__(256, 6) void triplet_kernel(const uint4* __restrict__ q8,
                                                         const void* __restrict__ trip_raw,
                                                         const __half* __restrict__ sqh,
                                                         const int* __restrict__ flag,
                                                         float* __restrict__ out,
                                                         int T, int N) {
    __shared__ uint4 sq_u4[NROWS * 2 / 16]; // 16 KB fp16 sq
    {
        const uint4* src = (const uint4*)sqh;
        int nvec = N * 2 / 16;
        for (int t = threadIdx.x; t < nvec; t += BLOCK) sq_u4[t] = src[t];
    }
    __syncthreads();
    const __half* sqs = (const __half*)sq_u4;

    const int lane = threadIdx.x & 63;
    const int sub = lane & 7;   // lane within 8-group
    const int g8 = lane >> 3;   // group 0..7
    const int wave = blockIdx.x * (BLOCK / 64) + (threadIdx.x >> 6);
    const int stride = gridDim.x * (BLOCK / 64) * 16;
    const bool m32 = (flag[0] != 0);
    const int* __restrict__ t32 = (const int*)trip_raw;
    const long long* __restrict__ t64 = (const long long*)trip_raw;

    int i0, j0, k0, i1, j1, k1;
    {
        int t0 = wave * 16;
        int tA = (t0 + g8) < T ? (t0 + g8) : T - 1;
        int tB = (t0 + 8 + g8) < T ? (t0 + 8 + g8) : T - 1;
        if (m32) {
            i0 = t32[3 * tA]; j0 = t32[3 * tA + 1]; k0 = t32[3 * tA + 2];
            i1 = t32[3 * tB]; j1 = t32[3 * tB + 1]; k1 = t32[3 * tB + 2];
        } else {
            i0 = (int)t64[3 * tA]; j0 = (int)t64[3 * tA + 1]; k0 = (int)t64[3 * tA + 2];
            i1 = (int)t64[3 * tB]; j1 = (int)t64[3 * tB + 1]; k1 = (int)t64[3 * tB + 2];
        }
    }

    double lsum = 0.0;
    for (int tb = wave * 16; tb < T; tb += stride) {
        uint4 A0 = q8[(size_t)i0 * 8 + sub];
        uint4 B0 = q8[(size_t)j0 * 8 + sub];
        uint4 C0 = q8[(size_t)k0 * 8 + sub];
        uint4 A1 = q8[(size_t)i1 * 8 + sub];
        uint4 B1 = q8[(size_t)j1 * 8 + sub];
        uint4 C1 = q8[(size_t)k1 * 8 + sub];
        float sqj0 = __half2float(sqs[j0]);
        float sqk0 = __half2float(sqs[k0]);
        float sqj1 = __half2float(sqs[j1]);
        float sqk1 = __half2float(sqs[k1]);
        bool v0 = (tb + g8) < T;
        bool v1 = (tb + 8 + g8) < T;

        // prefetch next iteration's indices (independent of row loads)
        int tn = tb + stride;
        int tA = (tn + g8) < T ? (tn + g8) : T - 1;
        int tB = (tn + 8 + g8) < T ? (tn + 8 + g8) : T - 1;
        if (m32) {
            i0 = t32[3 * tA]; j0 = t32[3 * tA + 1]; k0 = t32[3 * tA + 2];
            i1 = t32[3 * tB]; j1 = t32[3 * tB + 1]; k1 = t32[3 * tB + 2];
        } else {
            i0 = (int)t64[3 * tA]; j0 = (int)t64[3 * tA + 1]; k0 = (int)t64[3 * tA + 2];
            i1 = (int)t64[3 * tB]; j1 = (int)t64[3 * tB + 1]; k1 = (int)t64[3 * tB + 2];
        }

        int dd0 = dot16B(A0, B0) - dot16B(A0, C0);
        int dd1 = dot16B(A1, B1) - dot16B(A1, C1);
        dd0 += __shfl_xor(dd0, 1); dd1 += __shfl_xor(dd1, 1);
        dd0 += __shfl_xor(dd0, 2); dd1 += __shfl_xor(dd1, 2);
        dd0 += __shfl_xor(dd0, 4); dd1 += __shfl_xor(dd1, 4);

        float z0 = (sqj0 - sqk0) - TWO_S2 * (float)dd0;
        float z1 = (sqj1 - sqk1) - TWO_S2 * (float)dd1;
        float loss0 = fmaxf(z0, 0.0f) + __logf(1.0f + __expf(-fabsf(z0)));
        float loss1 = fmaxf(z1, 0.0f) + __logf(1.0f + __expf(-fabsf(z1)));
        lsum += (v0 ? (double)loss0 : 0.0) + (v1 ? (double)loss1 : 0.0);
    }
#pragma unroll
    for (int m = 1; m < 64; m <<= 1) lsum += __shfl_xor(lsum, m);
    if (lane == 0)
        atomicAdd(out, (float)(lsum / (8.0 * (double)T)));
}

extern "C" void kernel_launch(void* const* d_in, const int* in_sizes, int n_in,
                              void* d_out, int out_size, void* d_ws, size_t ws_size,
                              hipStream_t stream) {
    const float* feat = (const float*)d_in[0];
    const void* trip = d_in[1];
    int N = in_sizes[0] / D;  // 8192
    int T = in_sizes[1] / 3;  // 1,000,000

    char* ws = (char*)d_ws;
    int* flag = (int*)ws;
    __half* sqh = (__half*)(ws + 256);
    size_t q8_off = (256 + 2 * (size_t)N + 255) & ~(size_t)255;
    unsigned* q8 = (unsigned*)(ws + q8_off);
    float* out = (float*)d_out;

    int prep_blocks = (N * 32) / 256 + 1; // last block: dtype detect + out zero
    prep_kernel<<<prep_blocks, 256, 0, stream>>>(feat, (const unsigned long long*)trip,
                                                 in_sizes[1], sqh, q8, flag, out, N);
    triplet_kernel<<<MAIN_BLOCKS, BLOCK, 0, stream>>>((const uint4*)q8, trip, sqh, flag,
                                                      out, T, N);
}

// Round 8
// 101.922 us; speedup vs baseline: 1.7468x; 1.5988x over previous
//
#include <hip/hip_runtime.h>
#include <hip/hip_fp16.h>
#include <math.h>

constexpr int D = 128;
constexpr int MAIN_BLOCKS = 1536;  // 6 blocks/CU
constexpr int BLOCK = 256;
constexpr int NWAVES = MAIN_BLOCKS * (BLOCK / 64); // 6144
constexpr int NROWS = 8192;

#define QSCALE 25.4f            // 127/5
#define TWO_S2 (2.0f * (5.0f / 127.0f) * (5.0f / 127.0f))

// LESSONS ENCODED HERE:
//  - R6: indexed local arrays w/ conditional writes -> scratch spill (62MB
//    WRITE_SIZE). All loop state must be named scalars.
//  - R7: 6144 same-address atomicAdd finalize -> ~75us serialized drain tail
//    (cross-XCD same-line atomics). Use coalesced partial[] + finalize kernel.
//  - R4/R5: 4-lane groups (one 64B line per instr-group) is the fastest
//    gather shape; 8-lane/128B-group regressed.

#if __has_builtin(__builtin_amdgcn_sdot4)
__device__ inline int dot4(unsigned a, unsigned b, int c) {
    return __builtin_amdgcn_sdot4(a, b, c, false);
}
#else
__device__ inline int dot4(unsigned a, unsigned b, int c) {
    c += (int)(char)(a) * (int)(char)(b);
    c += (int)(char)(a >> 8) * (int)(char)(b >> 8);
    c += (int)(char)(a >> 16) * (int)(char)(b >> 16);
    c += (int)(char)(a >> 24) * (int)(char)(b >> 24);
    return c;
}
#endif

__device__ inline int dot_rows(uint4 a0, uint4 a1, uint4 b0, uint4 b1) {
    int d = 0;
    d = dot4(a0.x, b0.x, d); d = dot4(a0.y, b0.y, d);
    d = dot4(a0.z, b0.z, d); d = dot4(a0.w, b0.w, d);
    d = dot4(a1.x, b1.x, d); d = dot4(a1.y, b1.y, d);
    d = dot4(a1.z, b1.z, d); d = dot4(a1.w, b1.w, d);
    return d;
}

// prep: per row compute fp32 sq (exact) -> fp16 table, and int8-quantized row.
// Extra last block runs the int64-vs-int32 triplet dtype detection.
__global__ __launch_bounds__(256) void prep_kernel(const float* __restrict__ feat,
                                                   const unsigned long long* __restrict__ trip,
                                                   int n_slots,
                                                   __half* __restrict__ sqh,
                                                   unsigned* __restrict__ q8,
                                                   int* __restrict__ flag, int N) {
    if (blockIdx.x == gridDim.x - 1) {
        if (threadIdx.x < 64) {
            int cnt = n_slots < 2048 ? n_slots : 2048;
            bool big = false;
            for (int idx = threadIdx.x; idx < cnt; idx += 64)
                big |= (trip[idx] >> 32) != 0ULL;
            unsigned long long b = __ballot(big);
            if (threadIdx.x == 0) flag[0] = (b != 0ULL) ? 1 : 0; // 1 => int32
        }
        return;
    }
    int gidx = blockIdx.x * 256 + threadIdx.x;
    int row = gidx >> 5, lane = gidx & 31;
    if (row >= N) return;
    float4 v = ((const float4*)(feat + (size_t)row * D))[lane];
    float s = v.x * v.x + v.y * v.y + v.z * v.z + v.w * v.w;
#pragma unroll
    for (int m = 16; m >= 1; m >>= 1) s += __shfl_xor(s, m);
    if (lane == 0) sqh[row] = __float2half(s);
    int q0 = __float2int_rn(fminf(fmaxf(v.x * QSCALE, -127.f), 127.f));
    int q1 = __float2int_rn(fminf(fmaxf(v.y * QSCALE, -127.f), 127.f));
    int q2 = __float2int_rn(fminf(fmaxf(v.z * QSCALE, -127.f), 127.f));
    int q3 = __float2int_rn(fminf(fmaxf(v.w * QSCALE, -127.f), 127.f));
    unsigned p = (q0 & 255) | ((q1 & 255) << 8) | ((q2 & 255) << 16) | ((q3 & 255) << 24);
    q8[(size_t)row * 32 + lane] = p;
}

// 4 lanes/triplet, 2x unrolled: 32 triplets/wave/iter, 12 row-loads in flight.
// Index loads software-pipelined one iteration ahead.
// z = (sq_j - sq_k) - 2*S^2*(dot(qi,qj) - dot(qi,qk)); sq_i cancels exactly.
__global__ __launch_bounds__(256, 6) void triplet_kernel(const uint4* __restrict__ q8,
                                                         const void* __restrict__ trip_raw,
                                                         const __half* __restrict__ sqh,
                                                         const int* __restrict__ flag,
                                                         double* __restrict__ partial,
                                                         int T, int N) {
    __shared__ uint4 sq_u4[NROWS * 2 / 16]; // 16 KB of fp16 sq
    {
        const uint4* src = (const uint4*)sqh;
        int nvec = N * 2 / 16;
        for (int t = threadIdx.x; t < nvec; t += BLOCK) sq_u4[t] = src[t];
    }
    __syncthreads();
    const __half* sqs = (const __half*)sq_u4;

    const int lane = threadIdx.x & 63;
    const int sub = lane & 3;
    const int g = lane >> 2;  // 0..15
    const int wave = blockIdx.x * (BLOCK / 64) + (threadIdx.x >> 6);
    const int stride = gridDim.x * (BLOCK / 64) * 32;
    const bool m32 = (flag[0] != 0);
    const int* __restrict__ t32 = (const int*)trip_raw;
    const long long* __restrict__ t64 = (const long long*)trip_raw;

    double lsum = 0.0;
    int iA, jA, kA, iB, jB, kB;
    {
        int t0 = wave * 32;
        int tA = (t0 + g) < T ? (t0 + g) : T - 1;
        int tB = (t0 + 16 + g) < T ? (t0 + 16 + g) : T - 1;
        if (m32) {
            iA = t32[3 * tA]; jA = t32[3 * tA + 1]; kA = t32[3 * tA + 2];
            iB = t32[3 * tB]; jB = t32[3 * tB + 1]; kB = t32[3 * tB + 2];
        } else {
            iA = (int)t64[3 * tA]; jA = (int)t64[3 * tA + 1]; kA = (int)t64[3 * tA + 2];
            iB = (int)t64[3 * tB]; jB = (int)t64[3 * tB + 1]; kB = (int)t64[3 * tB + 2];
        }
    }

    for (int tb = wave * 32; tb < T; tb += stride) {
        // row = 8 uint4; lane sub reads slots sub and sub+4 -> each instruction's
        // 4-lane group covers one contiguous 64B line. 12 independent loads.
        const uint4* pAi = q8 + (size_t)iA * 8 + sub;
        const uint4* pAj = q8 + (size_t)jA * 8 + sub;
        const uint4* pAk = q8 + (size_t)kA * 8 + sub;
        const uint4* pBi = q8 + (size_t)iB * 8 + sub;
        const uint4* pBj = q8 + (size_t)jB * 8 + sub;
        const uint4* pBk = q8 + (size_t)kB * 8 + sub;
        uint4 Aa0 = pAi[0], Aa1 = pAi[4];
        uint4 Ab0 = pAj[0], Ab1 = pAj[4];
        uint4 Ac0 = pAk[0], Ac1 = pAk[4];
        uint4 Ba0 = pBi[0], Ba1 = pBi[4];
        uint4 Bb0 = pBj[0], Bb1 = pBj[4];
        uint4 Bc0 = pBk[0], Bc1 = pBk[4];

        // LDS sq reads (use indices before they're overwritten by prefetch)
        float sqjA = __half2float(sqs[jA]);
        float sqkA = __half2float(sqs[kA]);
        float sqjB = __half2float(sqs[jB]);
        float sqkB = __half2float(sqs[kB]);
        bool vA = (tb + g) < T;
        bool vB = (tb + 16 + g) < T;

        // prefetch next iteration's indices (independent of row loads)
        int tn = tb + stride;
        int tA = (tn + g) < T ? (tn + g) : T - 1;
        int tB = (tn + 16 + g) < T ? (tn + 16 + g) : T - 1;
        if (m32) {
            iA = t32[3 * tA]; jA = t32[3 * tA + 1]; kA = t32[3 * tA + 2];
            iB = t32[3 * tB]; jB = t32[3 * tB + 1]; kB = t32[3 * tB + 2];
        } else {
            iA = (int)t64[3 * tA]; jA = (int)t64[3 * tA + 1]; kA = (int)t64[3 * tA + 2];
            iB = (int)t64[3 * tB]; jB = (int)t64[3 * tB + 1]; kB = (int)t64[3 * tB + 2];
        }

        int ddA = dot_rows(Aa0, Aa1, Ab0, Ab1) - dot_rows(Aa0, Aa1, Ac0, Ac1);
        int ddB = dot_rows(Ba0, Ba1, Bb0, Bb1) - dot_rows(Ba0, Ba1, Bc0, Bc1);
        ddA += __shfl_xor(ddA, 1); ddB += __shfl_xor(ddB, 1);
        ddA += __shfl_xor(ddA, 2); ddB += __shfl_xor(ddB, 2);

        float zA = (sqjA - sqkA) - TWO_S2 * (float)ddA;
        float zB = (sqjB - sqkB) - TWO_S2 * (float)ddB;
        float lossA = fmaxf(zA, 0.0f) + __logf(1.0f + __expf(-fabsf(zA)));
        float lossB = fmaxf(zB, 0.0f) + __logf(1.0f + __expf(-fabsf(zB)));
        lsum += (vA ? (double)lossA : 0.0) + (vB ? (double)lossB : 0.0);
    }
#pragma unroll
    for (int m = 1; m < 64; m <<= 1) lsum += __shfl_xor(lsum, m);
    if (lane == 0) partial[wave] = lsum;
}

__global__ __launch_bounds__(256) void finalize_kernel(const double* __restrict__ partial,
                                                       int nw, float* __restrict__ out,
                                                       int T) {
    __shared__ double sm[256];
    double s = 0.0;
    for (int i = threadIdx.x; i < nw; i += blockDim.x) s += partial[i];
    sm[threadIdx.x] = s;
    __syncthreads();
    for (int w = 128; w >= 1; w >>= 1) {
        if ((int)threadIdx.x < w) sm[threadIdx.x] += sm[threadIdx.x + w];
        __syncthreads();
    }
    // each triplet accumulated 4x (once per lane of its 4-group)
    if (threadIdx.x == 0) out[0] = (float)(sm[0] / (4.0 * (double)T));
}

extern "C" void kernel_launch(void* const* d_in, const int* in_sizes, int n_in,
                              void* d_out, int out_size, void* d_ws, size_t ws_size,
                              hipStream_t stream) {
    const float* feat = (const float*)d_in[0];
    const void* trip = d_in[1];
    int N = in_sizes[0] / D;  // 8192
    int T = in_sizes[1] / 3;  // 1,000,000

    char* ws = (char*)d_ws;
    int* flag = (int*)ws;
    double* partial = (double*)(ws + 256);
    __half* sqh = (__half*)(ws + 256 + 8 * (size_t)NWAVES);
    size_t q8_off = (256 + 8 * (size_t)NWAVES + 2 * (size_t)N + 255) & ~(size_t)255;
    unsigned* q8 = (unsigned*)(ws + q8_off);
    float* out = (float*)d_out;

    int prep_blocks = (N * 32) / 256 + 1; // last block does dtype detection
    prep_kernel<<<prep_blocks, 256, 0, stream>>>(feat, (const unsigned long long*)trip,
                                                 in_sizes[1], sqh, q8, flag, N);
    triplet_kernel<<<MAIN_BLOCKS, BLOCK, 0, stream>>>((const uint4*)q8, trip, sqh, flag,
                                                      partial, T, N);
    finalize_kernel<<<1, 256, 0, stream>>>(partial, NWAVES, out, T);
}